// Round 7
// baseline (2835.747 us; speedup 1.0000x reference)
//
#include <hip/hip_runtime.h>
#include <math.h>

static constexpr int N = 8192;
static constexpr int M = 256;
static constexpr float SHIFT = 96.0f;

typedef __attribute__((ext_vector_type(8))) short bf16x8;
typedef __attribute__((ext_vector_type(4))) float f32x4;

__device__ __forceinline__ unsigned short f2bf(float x) {
  unsigned int u = __builtin_bit_cast(unsigned int, x);
  u += 0x7fffu + ((u >> 16) & 1u);
  return (unsigned short)(u >> 16);
}
__device__ __forceinline__ float bf2f(unsigned short h) {
  unsigned int u = ((unsigned int)h) << 16;
  return __builtin_bit_cast(float, u);
}
__device__ __forceinline__ f32x4 mfma16(bf16x8 a, bf16x8 b, f32x4 c) {
  return __builtin_amdgcn_mfma_f32_16x16x32_bf16(a, b, c, 0, 0, 0);
}
__device__ __forceinline__ bf16x8 ld8(const unsigned short* p) {
  return *reinterpret_cast<const bf16x8*>(p);
}

// ---------------------------------------------------------------------------
__global__ void zero_f32(float* __restrict__ p, int n4) {
  int i = blockIdx.x * 256 + threadIdx.x;
  if (i < n4) reinterpret_cast<float4*>(p)[i] = float4{0.f, 0.f, 0.f, 0.f};
}

// ---------------------------------------------------------------------------
// Ap = audio @ W^T (fp32 VALU, 0.54 G-FMA), writes bf16 hi/lo.
// ---------------------------------------------------------------------------
__global__ __launch_bounds__(256) void gemm_ap(const float* __restrict__ A,
                                               const float* __restrict__ B,
                                               unsigned short* __restrict__ Ch,
                                               unsigned short* __restrict__ Cl) {
  __shared__ float As[32 * 68];
  __shared__ float Bs[32 * 68];
  const int tid = threadIdx.x;
  const int ty = tid >> 4, tx = tid & 15;
  const int row0 = blockIdx.x * 64, col0 = blockIdx.y * 64;
  float acc[4][4] = {};
  for (int k0 = 0; k0 < M; k0 += 32) {
#pragma unroll
    for (int l = 0; l < 8; ++l) {
      int idx = tid + l * 256;
      int r = idx >> 5, c = idx & 31;
      As[c * 68 + r] = A[(size_t)(row0 + r) * M + k0 + c];
      Bs[c * 68 + r] = B[(size_t)(col0 + r) * M + k0 + c];
    }
    __syncthreads();
#pragma unroll
    for (int kk = 0; kk < 32; ++kk) {
      float4 a = *(const float4*)(As + kk * 68 + ty * 4);
      float4 b = *(const float4*)(Bs + kk * 68 + tx * 4);
      float av[4] = {a.x, a.y, a.z, a.w}, bv[4] = {b.x, b.y, b.z, b.w};
#pragma unroll
      for (int r = 0; r < 4; ++r)
#pragma unroll
        for (int c = 0; c < 4; ++c) acc[r][c] = fmaf(av[r], bv[c], acc[r][c]);
    }
    __syncthreads();
  }
#pragma unroll
  for (int r = 0; r < 4; ++r)
#pragma unroll
    for (int c = 0; c < 4; ++c) {
      float x = acc[r][c];
      unsigned short h = f2bf(x);
      size_t o = (size_t)(row0 + ty * 4 + r) * M + col0 + tx * 4 + c;
      Ch[o] = h;
      Cl[o] = f2bf(x - bf2f(h));
    }
}

// ---------------------------------------------------------------------------
// Tiled transpose (hi+lo) + optional row-major hi/lo split.
// ---------------------------------------------------------------------------
__global__ __launch_bounds__(256) void trsplit(const float* __restrict__ src,
                                               unsigned short* rh, unsigned short* rl,
                                               unsigned short* __restrict__ th,
                                               unsigned short* __restrict__ tl) {
  __shared__ float T[64][65];
  const int i0 = blockIdx.x * 64, m0 = blockIdx.y * 64;
  const int tid = threadIdx.x;
#pragma unroll
  for (int l = 0; l < 16; ++l) {
    int idx = tid + l * 256;
    int r = idx >> 6, c = idx & 63;
    float x = src[(size_t)(i0 + r) * M + m0 + c];
    T[r][c] = x;
    if (rh != nullptr) {
      unsigned short h = f2bf(x);
      size_t o = (size_t)(i0 + r) * M + m0 + c;
      rh[o] = h;
      rl[o] = f2bf(x - bf2f(h));
    }
  }
  __syncthreads();
#pragma unroll
  for (int l = 0; l < 16; ++l) {
    int idx = tid + l * 256;
    int r = idx >> 6, c = idx & 63;  // r: m-local, c: i-local
    float x = T[c][r];
    unsigned short h = f2bf(x);
    size_t o = (size_t)(m0 + r) * N + i0 + c;
    th[o] = h;
    tl[o] = f2bf(x - bf2f(h));
  }
}

// ---------------------------------------------------------------------------
// Stats: 1-D grid 1024, XCD-swizzled: p = b>>4 (row panel), q = b&15
// (512-col chunk). xcd = b%8 -> each XCD sees only q in {x, x+8}:
// its Vh/Vl working set is 2 x 1MB -> L2-resident.
// ---------------------------------------------------------------------------
__global__ __launch_bounds__(512, 4) void stats_mfma(
    const unsigned short* __restrict__ Aph, const unsigned short* __restrict__ Apl,
    const unsigned short* __restrict__ Vh, const unsigned short* __restrict__ Vl,
    float* __restrict__ rps, float* __restrict__ cps) {
  __shared__ float cred[8][64];
  const int tid = threadIdx.x;
  const int w = tid >> 6, l = tid & 63;
  const int lm = l & 15, lk = l >> 4;
  const int b = blockIdx.x;
  const int p = b >> 4, q = b & 15;
  const int arow = p * 128 + w * 16 + lm;

  bf16x8 ah[8];
#pragma unroll
  for (int kk = 0; kk < 8; ++kk) ah[kk] = ld8(Aph + (size_t)arow * M + kk * 32 + lk * 8);
  const unsigned short* alp = Apl + (size_t)arow * M + lk * 8;

  float rsum[4] = {0.f, 0.f, 0.f, 0.f};

  for (int jt = 0; jt < 8; ++jt) {
    const int j0 = q * 512 + jt * 64;
    f32x4 acc[4];
#pragma unroll
    for (int js = 0; js < 4; ++js) acc[js] = f32x4{0.f, 0.f, 0.f, 0.f};
#pragma unroll
    for (int kk = 0; kk < 8; ++kk) {
      bf16x8 alv = ld8(alp + kk * 32);
#pragma unroll
      for (int js = 0; js < 4; ++js) {
        size_t vo = (size_t)(j0 + js * 16 + lm) * M + kk * 32 + lk * 8;
        bf16x8 bh = ld8(Vh + vo);
        bf16x8 bl = ld8(Vl + vo);
        acc[js] = mfma16(ah[kk], bh, acc[js]);
        acc[js] = mfma16(ah[kk], bl, acc[js]);
        acc[js] = mfma16(alv, bh, acc[js]);
      }
    }
#pragma unroll
    for (int js = 0; js < 4; ++js) {
      float e0 = __expf(acc[js][0] - SHIFT), e1 = __expf(acc[js][1] - SHIFT);
      float e2 = __expf(acc[js][2] - SHIFT), e3 = __expf(acc[js][3] - SHIFT);
      rsum[0] += e0; rsum[1] += e1; rsum[2] += e2; rsum[3] += e3;
      float c = e0 + e1 + e2 + e3;
      c += __shfl_xor(c, 16);
      c += __shfl_xor(c, 32);
      if (lk == 0) cred[w][js * 16 + lm] = c;
    }
    __syncthreads();
    if (tid < 64) {
      float c = 0.f;
#pragma unroll
      for (int ww = 0; ww < 8; ++ww) c += cred[ww][tid];
      cps[(size_t)p * N + j0 + tid] = c;
    }
    __syncthreads();
  }
#pragma unroll
  for (int r = 0; r < 4; ++r) {
    float s = rsum[r];
    s += __shfl_xor(s, 1);
    s += __shfl_xor(s, 2);
    s += __shfl_xor(s, 4);
    s += __shfl_xor(s, 8);
    if (lm == 0) rps[(size_t)q * N + p * 128 + w * 16 + lk * 4 + r] = s;
  }
}

__global__ void row_inv(const float* __restrict__ rps, float* __restrict__ rinv) {
  int i = blockIdx.x * 256 + threadIdx.x;
  float s = 0.f;
#pragma unroll
  for (int q = 0; q < 16; ++q) s += rps[(size_t)q * N + i];
  rinv[i] = 1.f / s;
}
__global__ void col_inv(const float* __restrict__ cps, float* __restrict__ cinv) {
  int j = blockIdx.x * 256 + threadIdx.x;
  float s = 0.f;
  for (int p = 0; p < 64; ++p) s += cps[(size_t)p * N + j];
  cinv[j] = 1.f / s;
}

// ---------------------------------------------------------------------------
// out_audio: d_audio[i,m] = sum_j E(corr[i,j])*cinv[j] * audio[j,m]
// 1-D grid 1024, XCD-swizzled: jh = b&7 (one 1024-wide j-chunk per XCD ->
// Vh/Vl/AuT slices ~2MB, L2-resident), i0 = (b>>3)*64.
// Double-buffered W + pipeline: ONE barrier per jt.
// ---------------------------------------------------------------------------
__global__ __launch_bounds__(512, 4) void out_audio_m(
    const unsigned short* __restrict__ Aph, const unsigned short* __restrict__ Apl,
    const unsigned short* __restrict__ Vh, const unsigned short* __restrict__ Vl,
    const unsigned short* __restrict__ AuTh, const unsigned short* __restrict__ AuTl,
    const float* __restrict__ cinv, float* __restrict__ out) {
  __shared__ unsigned short Wh[2][64 * 72], Wl[2][64 * 72];
  const int tid = threadIdx.x;
  const int w = tid >> 6, l = tid & 63;
  const int lm = l & 15, lk = l >> 4;
  const int b = blockIdx.x;
  const int jh = b & 7;
  const int i0 = (b >> 3) * 64;
  const int isub = w & 3, half = w >> 2;
  const int m0 = half * 128;
  const int arow = i0 + isub * 16 + lm;

  bf16x8 ah[8];
#pragma unroll
  for (int kk = 0; kk < 8; ++kk) ah[kk] = ld8(Aph + (size_t)arow * M + kk * 32 + lk * 8);
  const unsigned short* alp = Apl + (size_t)arow * M + lk * 8;

  f32x4 dacc[8];
#pragma unroll
  for (int ms = 0; ms < 8; ++ms) dacc[ms] = f32x4{0.f, 0.f, 0.f, 0.f};

  auto corr_tile = [&](int j0, f32x4& c0, f32x4& c1) {
    c0 = f32x4{0.f, 0.f, 0.f, 0.f};
    c1 = f32x4{0.f, 0.f, 0.f, 0.f};
    const size_t r0base = (size_t)(j0 + half * 32 + lm) * M + lk * 8;
#pragma unroll
    for (int kk = 0; kk < 8; ++kk) {
      bf16x8 alv = ld8(alp + kk * 32);
      bf16x8 bh0 = ld8(Vh + r0base + kk * 32);
      bf16x8 bl0 = ld8(Vl + r0base + kk * 32);
      c0 = mfma16(ah[kk], bh0, c0);
      c0 = mfma16(ah[kk], bl0, c0);
      c0 = mfma16(alv, bh0, c0);
      bf16x8 bh1 = ld8(Vh + r0base + 16 * M + kk * 32);
      bf16x8 bl1 = ld8(Vl + r0base + 16 * M + kk * 32);
      c1 = mfma16(ah[kk], bh1, c1);
      c1 = mfma16(ah[kk], bl1, c1);
      c1 = mfma16(alv, bh1, c1);
    }
  };

  f32x4 cc0, cc1;
  corr_tile(jh * 1024, cc0, cc1);

  for (int jt = 0; jt < 16; ++jt) {
    const int j0 = jh * 1024 + jt * 64;
    const int buf = jt & 1;
    // weights -> LDS W[buf]
#pragma unroll
    for (int js2 = 0; js2 < 2; ++js2) {
      int js = half * 2 + js2;
      float ci = cinv[j0 + js * 16 + lm];
      f32x4 cc = js2 ? cc1 : cc0;
#pragma unroll
      for (int r = 0; r < 4; ++r) {
        float e = __expf(cc[r] - SHIFT) * ci;
        unsigned short h = f2bf(e);
        int irow = isub * 16 + lk * 4 + r;
        Wh[buf][irow * 72 + js * 16 + lm] = h;
        Wl[buf][irow * 72 + js * 16 + lm] = f2bf(e - bf2f(h));
      }
    }
    f32x4 n0 = cc0, n1 = cc1;
    if (jt + 1 < 16) corr_tile(j0 + 64, n0, n1);
    __syncthreads();
    // weighted: A = W rows, B = AuT hi/lo (global, L2-hot), 3-term
#pragma unroll
    for (int kk2 = 0; kk2 < 2; ++kk2) {
      bf16x8 wh = ld8(Wh[buf] + (isub * 16 + lm) * 72 + kk2 * 32 + lk * 8);
      bf16x8 wl = ld8(Wl[buf] + (isub * 16 + lm) * 72 + kk2 * 32 + lk * 8);
#pragma unroll
      for (int ms = 0; ms < 8; ++ms) {
        size_t bo = (size_t)(m0 + ms * 16 + lm) * N + j0 + kk2 * 32 + lk * 8;
        bf16x8 vh8 = ld8(AuTh + bo);
        bf16x8 vl8 = ld8(AuTl + bo);
        dacc[ms] = mfma16(wh, vh8, dacc[ms]);
        dacc[ms] = mfma16(wh, vl8, dacc[ms]);
        dacc[ms] = mfma16(wl, vh8, dacc[ms]);
      }
    }
    cc0 = n0;
    cc1 = n1;
  }
#pragma unroll
  for (int ms = 0; ms < 8; ++ms)
#pragma unroll
    for (int r = 0; r < 4; ++r) {
      int i = i0 + isub * 16 + lk * 4 + r;
      int m = m0 + ms * 16 + lm;
      atomicAdd(out + (size_t)i * (2 * M) + M + m, dacc[ms][r]);
    }
}

// ---------------------------------------------------------------------------
// out_video: d_video[i,m] = sum_j E(corr[j,i])*rinv[j] * video[j,m]
// Same 1-D XCD swizzle; Vs = video[i-panel] hi staged once; 1-barrier pipeline.
// ---------------------------------------------------------------------------
__global__ __launch_bounds__(512, 4) void out_video_m(
    const unsigned short* __restrict__ Aph, const unsigned short* __restrict__ Apl,
    const unsigned short* __restrict__ Vh, const unsigned short* __restrict__ Vl,
    const unsigned short* __restrict__ ViTh, const unsigned short* __restrict__ ViTl,
    const float* __restrict__ rinv, float* __restrict__ out) {
  __shared__ unsigned short Vs[64 * 264];
  __shared__ unsigned short Wh[2][64 * 72], Wl[2][64 * 72];
  const int tid = threadIdx.x;
  const int w = tid >> 6, l = tid & 63;
  const int lm = l & 15, lk = l >> 4;
  const int b = blockIdx.x;
  const int jh = b & 7;
  const int i0 = (b >> 3) * 64;
  const int jsub = w & 3, half = w >> 2;
  const int m0 = half * 128;

#pragma unroll
  for (int s = 0; s < 4; ++s) {
    int slot = tid + s * 512;
    int r = slot >> 5, c = slot & 31;
    *(bf16x8*)(Vs + r * 264 + c * 8) = ld8(Vh + (size_t)(i0 + r) * M + c * 8);
  }
  __syncthreads();

  f32x4 dacc[8];
#pragma unroll
  for (int ms = 0; ms < 8; ++ms) dacc[ms] = f32x4{0.f, 0.f, 0.f, 0.f};

  auto corr_tile = [&](int j0, f32x4& c0, f32x4& c1) {
    c0 = f32x4{0.f, 0.f, 0.f, 0.f};
    c1 = f32x4{0.f, 0.f, 0.f, 0.f};
    const int jrow = j0 + jsub * 16 + lm;
    const unsigned short* aphr = Aph + (size_t)jrow * M + lk * 8;
    const unsigned short* aplr = Apl + (size_t)jrow * M + lk * 8;
    const int ibase = half * 32 + lm;
#pragma unroll
    for (int kk = 0; kk < 8; ++kk) {
      bf16x8 ahf = ld8(aphr + kk * 32);
      bf16x8 alf = ld8(aplr + kk * 32);
      bf16x8 bh0 = ld8(Vs + ibase * 264 + kk * 32 + lk * 8);
      bf16x8 bl0 = ld8(Vl + (size_t)(i0 + ibase) * M + kk * 32 + lk * 8);
      c0 = mfma16(ahf, bh0, c0);
      c0 = mfma16(ahf, bl0, c0);
      c0 = mfma16(alf, bh0, c0);
      bf16x8 bh1 = ld8(Vs + (ibase + 16) * 264 + kk * 32 + lk * 8);
      bf16x8 bl1 = ld8(Vl + (size_t)(i0 + ibase + 16) * M + kk * 32 + lk * 8);
      c1 = mfma16(ahf, bh1, c1);
      c1 = mfma16(ahf, bl1, c1);
      c1 = mfma16(alf, bh1, c1);
    }
  };

  f32x4 cc0, cc1;
  corr_tile(jh * 1024, cc0, cc1);

  for (int jt = 0; jt < 16; ++jt) {
    const int j0 = jh * 1024 + jt * 64;
    const int buf = jt & 1;
    float rv[4];
#pragma unroll
    for (int r = 0; r < 4; ++r) rv[r] = rinv[j0 + jsub * 16 + lk * 4 + r];
#pragma unroll
    for (int is2 = 0; is2 < 2; ++is2) {
      int isub_i = half * 2 + is2;
      f32x4 cc = is2 ? cc1 : cc0;
#pragma unroll
      for (int r = 0; r < 4; ++r) {
        float e = __expf(cc[r] - SHIFT) * rv[r];
        unsigned short h = f2bf(e);
        int jl = jsub * 16 + lk * 4 + r;
        Wh[buf][(isub_i * 16 + lm) * 72 + jl] = h;
        Wl[buf][(isub_i * 16 + lm) * 72 + jl] = f2bf(e - bf2f(h));
      }
    }
    f32x4 n0 = cc0, n1 = cc1;
    if (jt + 1 < 16) corr_tile(j0 + 64, n0, n1);
    __syncthreads();
#pragma unroll
    for (int kk2 = 0; kk2 < 2; ++kk2) {
      bf16x8 wh = ld8(Wh[buf] + (jsub * 16 + lm) * 72 + kk2 * 32 + lk * 8);
      bf16x8 wl = ld8(Wl[buf] + (jsub * 16 + lm) * 72 + kk2 * 32 + lk * 8);
#pragma unroll
      for (int ms = 0; ms < 8; ++ms) {
        size_t bo = (size_t)(m0 + ms * 16 + lm) * N + j0 + kk2 * 32 + lk * 8;
        bf16x8 vh8 = ld8(ViTh + bo);
        bf16x8 vl8 = ld8(ViTl + bo);
        dacc[ms] = mfma16(wh, vh8, dacc[ms]);
        dacc[ms] = mfma16(wh, vl8, dacc[ms]);
        dacc[ms] = mfma16(wl, vh8, dacc[ms]);
      }
    }
    cc0 = n0;
    cc1 = n1;
  }
#pragma unroll
  for (int ms = 0; ms < 8; ++ms)
#pragma unroll
    for (int r = 0; r < 4; ++r) {
      int i = i0 + jsub * 16 + lk * 4 + r;
      int m = m0 + ms * 16 + lm;
      atomicAdd(out + (size_t)i * (2 * M) + m, dacc[ms][r]);
    }
}

// ---------------------------------------------------------------------------
__global__ void epilogue(float* __restrict__ out, const float* __restrict__ video,
                         const float* __restrict__ audio) {
  int idx = blockIdx.x * 256 + threadIdx.x;
  int i = idx >> 7;
  int c4 = idx & 127;
  float4 o = reinterpret_cast<float4*>(out)[(size_t)i * 128 + c4];
  const float* res = (c4 < 64) ? (video + (size_t)i * M + c4 * 4)
                               : (audio + (size_t)i * M + (c4 - 64) * 4);
  float4 rv = *reinterpret_cast<const float4*>(res);
  o.x = tanhf(o.x + rv.x);
  o.y = tanhf(o.y + rv.y);
  o.z = tanhf(o.z + rv.z);
  o.w = tanhf(o.w + rv.w);
  reinterpret_cast<float4*>(out)[(size_t)i * 128 + c4] = o;
}

// ---------------------------------------------------------------------------
extern "C" void kernel_launch(void* const* d_in, const int* in_sizes, int n_in,
                              void* d_out, int out_size, void* d_ws, size_t ws_size,
                              hipStream_t stream) {
  const float* audio = (const float*)d_in[0];
  const float* video = (const float*)d_in[1];
  const float* W = (const float*)d_in[2];
  float* out = (float*)d_out;

  const size_t nBF = (size_t)N * M * sizeof(unsigned short);  // 4 MB
  char* base = (char*)d_ws;
  unsigned short* Aph = (unsigned short*)(base);
  unsigned short* Apl = (unsigned short*)(base + nBF);
  unsigned short* Vh = (unsigned short*)(base + 2 * nBF);
  unsigned short* Vl = (unsigned short*)(base + 3 * nBF);
  unsigned short* ViTh = (unsigned short*)(base + 4 * nBF);
  unsigned short* ViTl = (unsigned short*)(base + 5 * nBF);
  unsigned short* AuTh = (unsigned short*)(base + 6 * nBF);
  unsigned short* AuTl = (unsigned short*)(base + 7 * nBF);
  float* rps = (float*)(base + 8 * nBF);   // 16*N
  float* cps = rps + 16 * (size_t)N;       // 64*N
  float* rinv = cps + 64 * (size_t)N;      // N
  float* cinv = rinv + N;                  // N
  const size_t need = 8 * nBF + (82 * (size_t)N) * sizeof(float);
  if (ws_size < need) return;

  zero_f32<<<dim3((N * 2 * M / 4 + 255) / 256), 256, 0, stream>>>(out, N * 2 * M / 4);
  gemm_ap<<<dim3(N / 64, M / 64), 256, 0, stream>>>(audio, W, Aph, Apl);
  trsplit<<<dim3(N / 64, M / 64), 256, 0, stream>>>(video, Vh, Vl, ViTh, ViTl);
  trsplit<<<dim3(N / 64, M / 64), 256, 0, stream>>>(audio, nullptr, nullptr, AuTh, AuTl);
  stats_mfma<<<1024, 512, 0, stream>>>(Aph, Apl, Vh, Vl, rps, cps);
  row_inv<<<N / 256, 256, 0, stream>>>(rps, rinv);
  col_inv<<<N / 256, 256, 0, stream>>>(cps, cinv);
  out_audio_m<<<1024, 512, 0, stream>>>(Aph, Apl, Vh, Vl, AuTh, AuTl, cinv, out);
  out_video_m<<<1024, 512, 0, stream>>>(Aph, Apl, Vh, Vl, ViTh, ViTl, rinv, out);
  epilogue<<<dim3(N * 2 * M / 4 / 256), 256, 0, stream>>>(out, video, audio);
}

// Round 8
// 913.799 us; speedup vs baseline: 3.1033x; 3.1033x over previous
//
#include <hip/hip_runtime.h>
#include <math.h>

static constexpr int N = 8192;
static constexpr int M = 256;
static constexpr float SHIFT = 96.0f;

typedef __attribute__((ext_vector_type(8))) short bf16x8;
typedef __attribute__((ext_vector_type(4))) float f32x4;

__device__ __forceinline__ unsigned short f2bf(float x) {
  unsigned int u = __builtin_bit_cast(unsigned int, x);
  u += 0x7fffu + ((u >> 16) & 1u);
  return (unsigned short)(u >> 16);
}
__device__ __forceinline__ float bf2f(unsigned short h) {
  unsigned int u = ((unsigned int)h) << 16;
  return __builtin_bit_cast(float, u);
}
__device__ __forceinline__ f32x4 mfma16(bf16x8 a, bf16x8 b, f32x4 c) {
  return __builtin_amdgcn_mfma_f32_16x16x32_bf16(a, b, c, 0, 0, 0);
}
__device__ __forceinline__ bf16x8 ld8(const unsigned short* p) {
  return *reinterpret_cast<const bf16x8*>(p);
}
__device__ __forceinline__ bf16x8 lds8(const unsigned short* p) {
  return *reinterpret_cast<const bf16x8*>(p);
}

// ---------------------------------------------------------------------------
__global__ void zero_f32(float* __restrict__ p, int n4) {
  int i = blockIdx.x * 256 + threadIdx.x;
  if (i < n4) reinterpret_cast<float4*>(p)[i] = float4{0.f, 0.f, 0.f, 0.f};
}

// ---------------------------------------------------------------------------
// Ap = audio @ W^T (fp32 VALU, 0.54 G-FMA), writes bf16 hi/lo.
// ---------------------------------------------------------------------------
__global__ __launch_bounds__(256) void gemm_ap(const float* __restrict__ A,
                                               const float* __restrict__ B,
                                               unsigned short* __restrict__ Ch,
                                               unsigned short* __restrict__ Cl) {
  __shared__ float As[32 * 68];
  __shared__ float Bs[32 * 68];
  const int tid = threadIdx.x;
  const int ty = tid >> 4, tx = tid & 15;
  const int row0 = blockIdx.x * 64, col0 = blockIdx.y * 64;
  float acc[4][4] = {};
  for (int k0 = 0; k0 < M; k0 += 32) {
#pragma unroll
    for (int l = 0; l < 8; ++l) {
      int idx = tid + l * 256;
      int r = idx >> 5, c = idx & 31;
      As[c * 68 + r] = A[(size_t)(row0 + r) * M + k0 + c];
      Bs[c * 68 + r] = B[(size_t)(col0 + r) * M + k0 + c];
    }
    __syncthreads();
#pragma unroll
    for (int kk = 0; kk < 32; ++kk) {
      float4 a = *(const float4*)(As + kk * 68 + ty * 4);
      float4 b = *(const float4*)(Bs + kk * 68 + tx * 4);
      float av[4] = {a.x, a.y, a.z, a.w}, bv[4] = {b.x, b.y, b.z, b.w};
#pragma unroll
      for (int r = 0; r < 4; ++r)
#pragma unroll
        for (int c = 0; c < 4; ++c) acc[r][c] = fmaf(av[r], bv[c], acc[r][c]);
    }
    __syncthreads();
  }
#pragma unroll
  for (int r = 0; r < 4; ++r)
#pragma unroll
    for (int c = 0; c < 4; ++c) {
      float x = acc[r][c];
      unsigned short h = f2bf(x);
      size_t o = (size_t)(row0 + ty * 4 + r) * M + col0 + tx * 4 + c;
      Ch[o] = h;
      Cl[o] = f2bf(x - bf2f(h));
    }
}

// ---------------------------------------------------------------------------
// Tiled transpose (hi+lo) + optional row-major hi/lo split.
// ---------------------------------------------------------------------------
__global__ __launch_bounds__(256) void trsplit(const float* __restrict__ src,
                                               unsigned short* rh, unsigned short* rl,
                                               unsigned short* __restrict__ th,
                                               unsigned short* __restrict__ tl) {
  __shared__ float T[64][65];
  const int i0 = blockIdx.x * 64, m0 = blockIdx.y * 64;
  const int tid = threadIdx.x;
#pragma unroll
  for (int l = 0; l < 16; ++l) {
    int idx = tid + l * 256;
    int r = idx >> 6, c = idx & 63;
    float x = src[(size_t)(i0 + r) * M + m0 + c];
    T[r][c] = x;
    if (rh != nullptr) {
      unsigned short h = f2bf(x);
      size_t o = (size_t)(i0 + r) * M + m0 + c;
      rh[o] = h;
      rl[o] = f2bf(x - bf2f(h));
    }
  }
  __syncthreads();
#pragma unroll
  for (int l = 0; l < 16; ++l) {
    int idx = tid + l * 256;
    int r = idx >> 6, c = idx & 63;  // r: m-local, c: i-local
    float x = T[c][r];
    unsigned short h = f2bf(x);
    size_t o = (size_t)(m0 + r) * N + i0 + c;
    th[o] = h;
    tl[o] = f2bf(x - bf2f(h));
  }
}

// ---------------------------------------------------------------------------
// Stats: per (128-row panel p, 512-col chunk q): V tile staged in LDS,
// corr via bf16x3 MFMA, E = exp(corr-96); additive row/col partial sums.
// ---------------------------------------------------------------------------
__global__ __launch_bounds__(512, 4) void stats_mfma(
    const unsigned short* __restrict__ Aph, const unsigned short* __restrict__ Apl,
    const unsigned short* __restrict__ Vh, const unsigned short* __restrict__ Vl,
    float* __restrict__ rps, float* __restrict__ cps) {
  __shared__ unsigned short Vsh[64 * 264];
  __shared__ unsigned short Vsl[64 * 264];
  __shared__ float cred[8][64];
  const int tid = threadIdx.x;
  const int w = tid >> 6, l = tid & 63;
  const int lm = l & 15, lk = l >> 4;
  const int b = blockIdx.x;
  const int p = b >> 4, q = b & 15;
  const int arow = p * 128 + w * 16 + lm;

  bf16x8 ah[8];
#pragma unroll
  for (int kk = 0; kk < 8; ++kk) ah[kk] = ld8(Aph + (size_t)arow * M + kk * 32 + lk * 8);
  const unsigned short* alp = Apl + (size_t)arow * M + lk * 8;

  float rsum[4] = {0.f, 0.f, 0.f, 0.f};

  for (int jt = 0; jt < 8; ++jt) {
    const int j0 = q * 512 + jt * 64;
    // stage V tile h+l
#pragma unroll
    for (int s = 0; s < 4; ++s) {
      int slot = tid + s * 512;
      int r = slot >> 5, c = slot & 31;
      *(bf16x8*)(Vsh + r * 264 + c * 8) = ld8(Vh + (size_t)(j0 + r) * M + c * 8);
      *(bf16x8*)(Vsl + r * 264 + c * 8) = ld8(Vl + (size_t)(j0 + r) * M + c * 8);
    }
    __syncthreads();

    f32x4 acc[4];
#pragma unroll
    for (int js = 0; js < 4; ++js) acc[js] = f32x4{0.f, 0.f, 0.f, 0.f};
#pragma unroll
    for (int kk = 0; kk < 8; ++kk) {
      bf16x8 alv = ld8(alp + kk * 32);
#pragma unroll
      for (int js = 0; js < 4; ++js) {
        const unsigned short* vsr = Vsh + (js * 16 + lm) * 264 + kk * 32 + lk * 8;
        const unsigned short* vlr = Vsl + (js * 16 + lm) * 264 + kk * 32 + lk * 8;
        bf16x8 bh = lds8(vsr);
        bf16x8 bl = lds8(vlr);
        acc[js] = mfma16(ah[kk], bh, acc[js]);
        acc[js] = mfma16(ah[kk], bl, acc[js]);
        acc[js] = mfma16(alv, bh, acc[js]);
      }
    }
#pragma unroll
    for (int js = 0; js < 4; ++js) {
      float e0 = __expf(acc[js][0] - SHIFT), e1 = __expf(acc[js][1] - SHIFT);
      float e2 = __expf(acc[js][2] - SHIFT), e3 = __expf(acc[js][3] - SHIFT);
      rsum[0] += e0; rsum[1] += e1; rsum[2] += e2; rsum[3] += e3;
      float c = e0 + e1 + e2 + e3;
      c += __shfl_xor(c, 16);
      c += __shfl_xor(c, 32);
      if (lk == 0) cred[w][js * 16 + lm] = c;
    }
    __syncthreads();
    if (tid < 64) {
      float c = 0.f;
#pragma unroll
      for (int ww = 0; ww < 8; ++ww) c += cred[ww][tid];
      cps[(size_t)p * N + j0 + tid] = c;
    }
    __syncthreads();
  }
#pragma unroll
  for (int r = 0; r < 4; ++r) {
    float s = rsum[r];
    s += __shfl_xor(s, 1);
    s += __shfl_xor(s, 2);
    s += __shfl_xor(s, 4);
    s += __shfl_xor(s, 8);
    if (lm == 0) rps[(size_t)q * N + p * 128 + w * 16 + lk * 4 + r] = s;
  }
}

__global__ void row_inv(const float* __restrict__ rps, float* __restrict__ rinv) {
  int i = blockIdx.x * 256 + threadIdx.x;
  float s = 0.f;
#pragma unroll
  for (int q = 0; q < 16; ++q) s += rps[(size_t)q * N + i];
  rinv[i] = 1.f / s;
}
__global__ void col_inv(const float* __restrict__ cps, float* __restrict__ cinv) {
  int j = blockIdx.x * 256 + threadIdx.x;
  float s = 0.f;
  for (int p = 0; p < 64; ++p) s += cps[(size_t)p * N + j];
  cinv[j] = 1.f / s;
}

// ---------------------------------------------------------------------------
// out_audio: d_audio[i,m] = sum_j E(corr[i,j])*cinv[j] * audio[j,m]
// All fragment streams via LDS: per jt stage V(h+l) and AuT(h+l) tiles;
// W bounce overlays dead V region. Phases: stage|corr|Wwrite|weighted.
// LDS = 141.3 KB, 1 block/CU, grid (128 i-panels x 2 j-chunks of 4096).
// ---------------------------------------------------------------------------
__global__ __launch_bounds__(512) void out_audio_m(
    const unsigned short* __restrict__ Aph, const unsigned short* __restrict__ Apl,
    const unsigned short* __restrict__ Vh, const unsigned short* __restrict__ Vl,
    const unsigned short* __restrict__ AuTh, const unsigned short* __restrict__ AuTl,
    const float* __restrict__ cinv, float* __restrict__ out) {
  __shared__ unsigned short SA[33792];  // V tile h+l [64][264]x2 ; W h+l overlay
  __shared__ unsigned short SB[36864];  // AuT tile h+l [256][72]x2
  unsigned short* Vsh = SA;
  unsigned short* Vsl = SA + 16896;
  unsigned short* Wh = SA;               // overlay (post-corr)
  unsigned short* Wl = SA + 4608;
  unsigned short* Ath = SB;
  unsigned short* Atl = SB + 18432;
  const int tid = threadIdx.x;
  const int w = tid >> 6, l = tid & 63;
  const int lm = l & 15, lk = l >> 4;
  const int i0 = blockIdx.x * 64;
  const int jc = blockIdx.y;  // chunk of 4096
  const int isub = w & 3, half = w >> 2;
  const int m0 = half * 128;
  const int arow = i0 + isub * 16 + lm;

  bf16x8 ah[8];
#pragma unroll
  for (int kk = 0; kk < 8; ++kk) ah[kk] = ld8(Aph + (size_t)arow * M + kk * 32 + lk * 8);
  const unsigned short* alp = Apl + (size_t)arow * M + lk * 8;

  f32x4 dacc[8];
#pragma unroll
  for (int ms = 0; ms < 8; ++ms) dacc[ms] = f32x4{0.f, 0.f, 0.f, 0.f};

  for (int jt = 0; jt < 64; ++jt) {
    const int j0 = jc * 4096 + jt * 64;
    // ---- stage V h+l and AuT h+l (coalesced) ----
#pragma unroll
    for (int s = 0; s < 4; ++s) {
      int slot = tid + s * 512;
      int r = slot >> 5, c = slot & 31;
      *(bf16x8*)(Vsh + r * 264 + c * 8) = ld8(Vh + (size_t)(j0 + r) * M + c * 8);
      *(bf16x8*)(Vsl + r * 264 + c * 8) = ld8(Vl + (size_t)(j0 + r) * M + c * 8);
      int row = slot >> 3, ch = slot & 7;
      *(bf16x8*)(Ath + row * 72 + ch * 8) = ld8(AuTh + (size_t)row * N + j0 + ch * 8);
      *(bf16x8*)(Atl + row * 72 + ch * 8) = ld8(AuTl + (size_t)row * N + j0 + ch * 8);
    }
    __syncthreads();
    // ---- corr tile [64 i x 64 j], 3-term ----
    f32x4 cc0 = f32x4{0.f, 0.f, 0.f, 0.f};
    f32x4 cc1 = f32x4{0.f, 0.f, 0.f, 0.f};
    const int jb = half * 32 + lm;
#pragma unroll
    for (int kk = 0; kk < 8; ++kk) {
      bf16x8 alv = ld8(alp + kk * 32);
      bf16x8 bh0 = lds8(Vsh + jb * 264 + kk * 32 + lk * 8);
      bf16x8 bl0 = lds8(Vsl + jb * 264 + kk * 32 + lk * 8);
      cc0 = mfma16(ah[kk], bh0, cc0);
      cc0 = mfma16(ah[kk], bl0, cc0);
      cc0 = mfma16(alv, bh0, cc0);
      bf16x8 bh1 = lds8(Vsh + (jb + 16) * 264 + kk * 32 + lk * 8);
      bf16x8 bl1 = lds8(Vsl + (jb + 16) * 264 + kk * 32 + lk * 8);
      cc1 = mfma16(ah[kk], bh1, cc1);
      cc1 = mfma16(ah[kk], bl1, cc1);
      cc1 = mfma16(alv, bh1, cc1);
    }
    __syncthreads();  // V reads done; W overlay safe
    // ---- weights -> LDS (overlay) ----
#pragma unroll
    for (int js2 = 0; js2 < 2; ++js2) {
      int js = half * 2 + js2;
      float ci = cinv[j0 + js * 16 + lm];
      f32x4 cc = js2 ? cc1 : cc0;
#pragma unroll
      for (int r = 0; r < 4; ++r) {
        float e = __expf(cc[r] - SHIFT) * ci;
        unsigned short h = f2bf(e);
        int irow = isub * 16 + lk * 4 + r;
        Wh[irow * 72 + js * 16 + lm] = h;
        Wl[irow * 72 + js * 16 + lm] = f2bf(e - bf2f(h));
      }
    }
    __syncthreads();
    // ---- weighted: A = W (LDS), B = AuT tile (LDS), 3-term ----
#pragma unroll
    for (int kk2 = 0; kk2 < 2; ++kk2) {
      bf16x8 wh = lds8(Wh + (isub * 16 + lm) * 72 + kk2 * 32 + lk * 8);
      bf16x8 wl = lds8(Wl + (isub * 16 + lm) * 72 + kk2 * 32 + lk * 8);
#pragma unroll
      for (int ms = 0; ms < 8; ++ms) {
        int mr = m0 + ms * 16 + lm;
        bf16x8 vh8 = lds8(Ath + mr * 72 + kk2 * 32 + lk * 8);
        bf16x8 vl8 = lds8(Atl + mr * 72 + kk2 * 32 + lk * 8);
        dacc[ms] = mfma16(wh, vh8, dacc[ms]);
        dacc[ms] = mfma16(wh, vl8, dacc[ms]);
        dacc[ms] = mfma16(wl, vh8, dacc[ms]);
      }
    }
    __syncthreads();  // weighted reads done; next stage safe
  }
#pragma unroll
  for (int ms = 0; ms < 8; ++ms)
#pragma unroll
    for (int r = 0; r < 4; ++r) {
      int i = i0 + isub * 16 + lk * 4 + r;
      int m = m0 + ms * 16 + lm;
      atomicAdd(out + (size_t)i * (2 * M) + M + m, dacc[ms][r]);
    }
}

// ---------------------------------------------------------------------------
// out_video: d_video[i,m] = sum_j E(corr[j,i])*rinv[j] * video[j,m]
// Staged: Ap tile h+l (per jt, W overlays), ViT tile h (per jt),
// video i-panel h (once). Global (hot sets): video-panel lo, ViT lo.
// ---------------------------------------------------------------------------
__global__ __launch_bounds__(512) void out_video_m(
    const unsigned short* __restrict__ Aph, const unsigned short* __restrict__ Apl,
    const unsigned short* __restrict__ Vh, const unsigned short* __restrict__ Vl,
    const unsigned short* __restrict__ ViTh, const unsigned short* __restrict__ ViTl,
    const float* __restrict__ rinv, float* __restrict__ out) {
  __shared__ unsigned short SA[33792];  // Ap tile h+l [64][264]x2 ; W overlay
  __shared__ unsigned short SB[18432];  // ViT tile h [256][72]
  __shared__ unsigned short SC[16896];  // video i-panel h [64][264] (static)
  unsigned short* Ash = SA;
  unsigned short* Asl = SA + 16896;
  unsigned short* Wh = SA;
  unsigned short* Wl = SA + 4608;
  unsigned short* Vts = SB;
  unsigned short* Vps = SC;
  const int tid = threadIdx.x;
  const int w = tid >> 6, l = tid & 63;
  const int lm = l & 15, lk = l >> 4;
  const int i0 = blockIdx.x * 64;
  const int jc = blockIdx.y;
  const int jsub = w & 3, half = w >> 2;
  const int m0 = half * 128;

  // stage video i-panel (hi) once
#pragma unroll
  for (int s = 0; s < 4; ++s) {
    int slot = tid + s * 512;
    int r = slot >> 5, c = slot & 31;
    *(bf16x8*)(Vps + r * 264 + c * 8) = ld8(Vh + (size_t)(i0 + r) * M + c * 8);
  }

  f32x4 dacc[8];
#pragma unroll
  for (int ms = 0; ms < 8; ++ms) dacc[ms] = f32x4{0.f, 0.f, 0.f, 0.f};

  for (int jt = 0; jt < 64; ++jt) {
    const int j0 = jc * 4096 + jt * 64;
    // ---- stage Ap tile h+l and ViT tile h ----
#pragma unroll
    for (int s = 0; s < 4; ++s) {
      int slot = tid + s * 512;
      int r = slot >> 5, c = slot & 31;
      *(bf16x8*)(Ash + r * 264 + c * 8) = ld8(Aph + (size_t)(j0 + r) * M + c * 8);
      *(bf16x8*)(Asl + r * 264 + c * 8) = ld8(Apl + (size_t)(j0 + r) * M + c * 8);
      int row = slot >> 3, ch = slot & 7;
      *(bf16x8*)(Vts + row * 72 + ch * 8) = ld8(ViTh + (size_t)row * N + j0 + ch * 8);
    }
    __syncthreads();
    // ---- corr tile [64 j x 64 i], 3-term ----
    f32x4 cc0 = f32x4{0.f, 0.f, 0.f, 0.f};
    f32x4 cc1 = f32x4{0.f, 0.f, 0.f, 0.f};
    const int jrl = jsub * 16 + lm;
    const int ibase = half * 32 + lm;
#pragma unroll
    for (int kk = 0; kk < 8; ++kk) {
      bf16x8 ahf = lds8(Ash + jrl * 264 + kk * 32 + lk * 8);
      bf16x8 alf = lds8(Asl + jrl * 264 + kk * 32 + lk * 8);
      bf16x8 bh0 = lds8(Vps + ibase * 264 + kk * 32 + lk * 8);
      bf16x8 bl0 = ld8(Vl + (size_t)(i0 + ibase) * M + kk * 32 + lk * 8);
      cc0 = mfma16(ahf, bh0, cc0);
      cc0 = mfma16(ahf, bl0, cc0);
      cc0 = mfma16(alf, bh0, cc0);
      bf16x8 bh1 = lds8(Vps + (ibase + 16) * 264 + kk * 32 + lk * 8);
      bf16x8 bl1 = ld8(Vl + (size_t)(i0 + ibase + 16) * M + kk * 32 + lk * 8);
      cc1 = mfma16(ahf, bh1, cc1);
      cc1 = mfma16(ahf, bl1, cc1);
      cc1 = mfma16(alf, bh1, cc1);
    }
    __syncthreads();  // Ap-tile reads done; W overlay safe
    // ---- weights -> LDS ----
    float rv[4];
#pragma unroll
    for (int r = 0; r < 4; ++r) rv[r] = rinv[j0 + jsub * 16 + lk * 4 + r];
#pragma unroll
    for (int is2 = 0; is2 < 2; ++is2) {
      int isub_i = half * 2 + is2;
      f32x4 cc = is2 ? cc1 : cc0;
#pragma unroll
      for (int r = 0; r < 4; ++r) {
        float e = __expf(cc[r] - SHIFT) * rv[r];
        unsigned short h = f2bf(e);
        int jl = jsub * 16 + lk * 4 + r;
        Wh[(isub_i * 16 + lm) * 72 + jl] = h;
        Wl[(isub_i * 16 + lm) * 72 + jl] = f2bf(e - bf2f(h));
      }
    }
    __syncthreads();
    // ---- weighted: A = W (LDS), B = ViT h (LDS) + ViT l (global hot) ----
#pragma unroll
    for (int kk2 = 0; kk2 < 2; ++kk2) {
      bf16x8 wh = lds8(Wh + (jsub * 16 + lm) * 72 + kk2 * 32 + lk * 8);
      bf16x8 wl = lds8(Wl + (jsub * 16 + lm) * 72 + kk2 * 32 + lk * 8);
#pragma unroll
      for (int ms = 0; ms < 8; ++ms) {
        int mr = m0 + ms * 16 + lm;
        bf16x8 vh8 = lds8(Vts + mr * 72 + kk2 * 32 + lk * 8);
        bf16x8 vl8 = ld8(ViTl + (size_t)mr * N + j0 + kk2 * 32 + lk * 8);
        dacc[ms] = mfma16(wh, vh8, dacc[ms]);
        dacc[ms] = mfma16(wh, vl8, dacc[ms]);
        dacc[ms] = mfma16(wl, vh8, dacc[ms]);
      }
    }
    __syncthreads();
  }
#pragma unroll
  for (int ms = 0; ms < 8; ++ms)
#pragma unroll
    for (int r = 0; r < 4; ++r) {
      int i = i0 + jsub * 16 + lk * 4 + r;
      int m = m0 + ms * 16 + lm;
      atomicAdd(out + (size_t)i * (2 * M) + m, dacc[ms][r]);
    }
}

// ---------------------------------------------------------------------------
__global__ void epilogue(float* __restrict__ out, const float* __restrict__ video,
                         const float* __restrict__ audio) {
  int idx = blockIdx.x * 256 + threadIdx.x;
  int i = idx >> 7;
  int c4 = idx & 127;
  float4 o = reinterpret_cast<float4*>(out)[(size_t)i * 128 + c4];
  const float* res = (c4 < 64) ? (video + (size_t)i * M + c4 * 4)
                               : (audio + (size_t)i * M + (c4 - 64) * 4);
  float4 rv = *reinterpret_cast<const float4*>(res);
  o.x = tanhf(o.x + rv.x);
  o.y = tanhf(o.y + rv.y);
  o.z = tanhf(o.z + rv.z);
  o.w = tanhf(o.w + rv.w);
  reinterpret_cast<float4*>(out)[(size_t)i * 128 + c4] = o;
}

// ---------------------------------------------------------------------------
extern "C" void kernel_launch(void* const* d_in, const int* in_sizes, int n_in,
                              void* d_out, int out_size, void* d_ws, size_t ws_size,
                              hipStream_t stream) {
  const float* audio = (const float*)d_in[0];
  const float* video = (const float*)d_in[1];
  const float* W = (const float*)d_in[2];
  float* out = (float*)d_out;

  const size_t nBF = (size_t)N * M * sizeof(unsigned short);  // 4 MB
  char* base = (char*)d_ws;
  unsigned short* Aph = (unsigned short*)(base);
  unsigned short* Apl = (unsigned short*)(base + nBF);
  unsigned short* Vh = (unsigned short*)(base + 2 * nBF);
  unsigned short* Vl = (unsigned short*)(base + 3 * nBF);
  unsigned short* ViTh = (unsigned short*)(base + 4 * nBF);
  unsigned short* ViTl = (unsigned short*)(base + 5 * nBF);
  unsigned short* AuTh = (unsigned short*)(base + 6 * nBF);
  unsigned short* AuTl = (unsigned short*)(base + 7 * nBF);
  float* rps = (float*)(base + 8 * nBF);   // 16*N
  float* cps = rps + 16 * (size_t)N;       // 64*N
  float* rinv = cps + 64 * (size_t)N;      // N
  float* cinv = rinv + N;                  // N
  const size_t need = 8 * nBF + (82 * (size_t)N) * sizeof(float);
  if (ws_size < need) return;

  zero_f32<<<dim3((N * 2 * M / 4 + 255) / 256), 256, 0, stream>>>(out, N * 2 * M / 4);
  gemm_ap<<<dim3(N / 64, M / 64), 256, 0, stream>>>(audio, W, Aph, Apl);
  trsplit<<<dim3(N / 64, M / 64), 256, 0, stream>>>(video, Vh, Vl, ViTh, ViTl);
  trsplit<<<dim3(N / 64, M / 64), 256, 0, stream>>>(audio, nullptr, nullptr, AuTh, AuTl);
  stats_mfma<<<1024, 512, 0, stream>>>(Aph, Apl, Vh, Vl, rps, cps);
  row_inv<<<N / 256, 256, 0, stream>>>(rps, rinv);
  col_inv<<<N / 256, 256, 0, stream>>>(cps, cinv);
  out_audio_m<<<dim3(N / 64, 2), 512, 0, stream>>>(Aph, Apl, Vh, Vl, AuTh, AuTl, cinv, out);
  out_video_m<<<dim3(N / 64, 2), 512, 0, stream>>>(Aph, Apl, Vh, Vl, ViTh, ViTl, rinv, out);
  epilogue<<<dim3(N * 2 * M / 4 / 256), 256, 0, stream>>>(out, video, audio);
}